// Round 4
// baseline (405.991 us; speedup 1.0000x reference)
//
#include <hip/hip_runtime.h>
#include <hip/hip_bf16.h>
#include <stdint.h>

// B=524288, H=64, D=1. fp32 in/out.
// R6b: resubmission of R6 (container failed twice -> infra suspected; kernel
// audited for OOB/hang/race hazards, none found). Structure:
//  - 1024-thr blocks (16 waves, 1 block/CU, 130 KB LDS), 512 rows/block,
//    wc staged once per block, ONE barrier.
//  - h0: coalesced float4 loads -> bf16 pack -> per-wave LDS bounce
//    (rotate-swizzled granules) -> ds_read_b128 fragments. Kills the
//    32-lines/instr TA scatter.
//  - c0: global_load_lds DMA of [16x16] fp32 slices, double-buffered per jh,
//    counted s_waitcnt vmcnt(2) (never drained mid-loop). Epilogue reads c0
//    from LDS.
//  - MFMA core, A-build, prescaled-bias epilogue, butterfly: unchanged (R5).

typedef __attribute__((ext_vector_type(8))) __bf16  bf16x8;
typedef __attribute__((ext_vector_type(4))) __bf16  bf16x4;
typedef __attribute__((ext_vector_type(8))) float   f32x8;
typedef __attribute__((ext_vector_type(4))) float   f32x4v;
typedef __attribute__((ext_vector_type(4))) float   floatx4;

__device__ __forceinline__ unsigned short f2bf_bits(float x){
    unsigned u = __builtin_bit_cast(unsigned, x);
    u = u + 0x7fffu + ((u >> 16) & 1u);          // RNE
    return (unsigned short)(u >> 16);
}

// size arg must stay a literal -> macro, not function parameter.
#define GLD_LDS16(gp, lp)                                                     \
    __builtin_amdgcn_global_load_lds(                                         \
        (const __attribute__((address_space(1))) void*)(const void*)(gp),     \
        (__attribute__((address_space(3))) void*)(void*)(lp), 16, 0, 0)

// ---------------------------------------------------------------------------
// Prep (unchanged, proven correct): Wc[256x128] bf16 in MFMA-B fragment
// order; biasc[n] = b_ih+b_hh+W_ih@b2 (raw; prescaling happens at staging).
// ---------------------------------------------------------------------------
__global__ __launch_bounds__(256) void prep_kernel(
    const float* __restrict__ W2, const float* __restrict__ b2,
    const float* __restrict__ W_ih, const float* __restrict__ W_hh,
    const float* __restrict__ b_ih, const float* __restrict__ b_hh,
    unsigned short* __restrict__ wc, float* __restrict__ biasc)
{
    __shared__ float W2s[64*64];
    __shared__ float b2s[64];
    __shared__ float wihs[16*64];
    const int tid = threadIdx.x;
    const int b   = blockIdx.x;          // 0..15

    for (int i = 0; i < 4; i++){
        int idx = i*1024 + tid*4;
        *(float4*)(W2s + idx) = *(const float4*)(W2 + idx);
    }
    if (tid < 64) b2s[tid] = b2[tid];
    {
        int idx = tid*4;
        *(float4*)(wihs + idx) = *(const float4*)(W_ih + b*16*64 + idx);
    }
    __syncthreads();

    const int nl = tid >> 4;
    const int n  = b*16 + nl;
    const int jg = tid & 15;
    const int j  = jg*4;
    const int T  = n >> 4;

    float a0=0.f, a1=0.f, a2=0.f, a3=0.f;
    for (int h = 0; h < 64; h++){
        float wv = wihs[nl*64 + h];
        const float* w2r = W2s + h*64 + j;
        a0 += wv*w2r[0]; a1 += wv*w2r[1]; a2 += wv*w2r[2]; a3 += wv*w2r[3];
    }
    auto store4 = [&](int k, float v0, float v1, float v2, float v3){
        int s    = k >> 5;
        int lane = ((k >> 3) & 3)*16 + (n & 15);
        int off  = (T*4 + s)*512 + lane*8 + (k & 7);
        ushort4 v; v.x=f2bf_bits(v0); v.y=f2bf_bits(v1); v.z=f2bf_bits(v2); v.w=f2bf_bits(v3);
        *(ushort4*)(wc + off) = v;
    };
    store4(j, a0, a1, a2, a3);
    {
        const float* src = W_hh + n*64 + j;
        store4(64 + j, src[0], src[1], src[2], src[3]);
    }
    if (jg == 0){
        float s = b_ih[n] + b_hh[n];
        for (int h = 0; h < 64; h++) s += wihs[nl*64 + h]*b2s[h];
        biasc[n] = s;
    }
}

// ---------------------------------------------------------------------------
// Main: 1024 threads = 16 waves, 512 rows/block, 1024 blocks.
// Wave w: rows [row0, row0+32) as two 16-row sets sharing B-frag ds_reads.
// ---------------------------------------------------------------------------
__global__ __launch_bounds__(1024, 4) void main_kernel(
    const float* __restrict__ grad, const float* __restrict__ param,
    const float* __restrict__ mom,  const float* __restrict__ h0,
    const float* __restrict__ c0,   const float* __restrict__ W1,
    const float* __restrict__ b1,   const float* __restrict__ Wout,
    const float* __restrict__ bout,
    const unsigned short* __restrict__ wc, const float* __restrict__ biasc,
    float* __restrict__ out)
{
    __shared__ __align__(16) unsigned short wc_l[32768];       // 64 KB
    __shared__ __align__(16) unsigned char  region[16*4096];   // 64 KB (4 KB/wave)
    __shared__ float  bias_l[256];   // prescaled: -log2e*b (i,f,o), +2log2e*b (g)
    __shared__ float4 w1p_l[64];     // {W1[j][0..2], b1[j]}
    __shared__ float  wout_l[64];

    const int tid  = threadIdx.x;
    const int lane = tid & 63;
    const int w    = tid >> 6;       // 0..15
    const int l15  = lane & 15;
    const int q    = lane >> 4;
    const long row0 = (long)blockIdx.x * 512 + w*32;
    unsigned char* Rb = region + w*4096;

    // ---- stage Wc + tables into LDS ----
    {
        const float4* src = (const float4*)wc;
        float4*       dst = (float4*)wc_l;
        #pragma unroll
        for (int i = 0; i < 4; i++)
            dst[i*1024 + tid] = src[i*1024 + tid];
    }
    if (tid < 256){
        float sc = ((tid >> 6) == 2) ? 2.885390082f : -1.442695041f;
        bias_l[tid] = sc * biasc[tid];
    } else if (tid < 320){
        int j = tid - 256;
        w1p_l[j] = make_float4(W1[j*3], W1[j*3+1], W1[j*3+2], b1[j]);
    } else if (tid < 384){
        wout_l[tid - 320] = Wout[tid - 320];
    }

    // ---- h0 coalesced loads, both sets (issued under wc staging) ----
    float4 hv0[4], hv1[4];
    {
        const float* base0 = h0 + row0*64;          // set0: 16 rows x 64
        const float* base1 = h0 + (row0+16)*64;     // set1
        #pragma unroll
        for (int j = 0; j < 4; j++){
            hv0[j] = *(const float4*)(base0 + (j*64 + lane)*4);
            hv1[j] = *(const float4*)(base1 + (j*64 + lane)*4);
        }
    }
    float g0 = grad[row0 + l15],      p0 = param[row0 + l15],      mo0 = mom[row0 + l15];
    float g1 = grad[row0 + 16 + l15], p1 = param[row0 + 16 + l15], mo1 = mom[row0 + 16 + l15];
    const float bout0 = bout[0];

    // ---- h0 bounce: bf16 pack + rotate-swizzled ds_write (per-wave region) ----
    // lane holds rows {j*4 + lane>>4}, col-quad c4 = lane&15 (4 floats each).
    // granule (16B = 8 cols bf16) c = c4>>1, half = c4&1; stored at
    // gr' = (c + row)&7 -> byte = set*2048 + row*128 + gr'*16 + half*8.
    {
        const int c    = (lane >> 1) & 7;
        const int half = lane & 1;
        const int rb   = lane >> 4;
        #pragma unroll
        for (int j = 0; j < 4; j++){
            int r  = j*4 + rb;
            int gp = (c + r) & 7;
            f32x4v t0; t0[0]=hv0[j].x; t0[1]=hv0[j].y; t0[2]=hv0[j].z; t0[3]=hv0[j].w;
            f32x4v t1; t1[0]=hv1[j].x; t1[1]=hv1[j].y; t1[2]=hv1[j].z; t1[3]=hv1[j].w;
            *(bf16x4*)(Rb + r*128 + gp*16 + half*8)        = __builtin_convertvector(t0, bf16x4);
            *(bf16x4*)(Rb + 2048 + r*128 + gp*16 + half*8) = __builtin_convertvector(t1, bf16x4);
        }
    }
    asm volatile("s_waitcnt lgkmcnt(0)" ::: "memory");   // bounce writes visible
    // fragment reads: afr2 = cols q*8..+8 (granule q), afr3 = granule q+4
    bf16x8 a2_0 = *(const bf16x8*)(Rb + l15*128 + (((q     + l15) & 7) << 4));
    bf16x8 a3_0 = *(const bf16x8*)(Rb + l15*128 + (((q + 4 + l15) & 7) << 4));
    bf16x8 a2_1 = *(const bf16x8*)(Rb + 2048 + l15*128 + (((q     + l15) & 7) << 4));
    bf16x8 a3_1 = *(const bf16x8*)(Rb + 2048 + l15*128 + (((q + 4 + l15) & 7) << 4));

    __syncthreads();   // wc_l / bias_l / w1p_l / wout_l ready (drains vmem too)

    // ---- c0 DMA: per-lane coalesced src, linear LDS dest, 1 KB per set/jh ----
    // slice jh: [16 rows][cols jh*16..+16] -> LDS [16][16] row-major.
    const int rr = lane >> 2, cc = lane & 3;
    const float* c0s0 = c0 + (row0 + rr)*64 + cc*4;
    const float* c0s1 = c0 + (row0 + 16 + rr)*64 + cc*4;
    GLD_LDS16(c0s0,      Rb);               // jh0 set0 -> buf0
    GLD_LDS16(c0s1,      Rb + 1024);        // jh0 set1
    GLD_LDS16(c0s0 + 16, Rb + 2048);        // jh1 set0 -> buf1
    GLD_LDS16(c0s1 + 16, Rb + 2048 + 1024); // jh1 set1

    // ---- A-fragment r-part build, both sets ----
    float m0 = fmaf(0.9f, mo0, g0);
    float m1 = fmaf(0.9f, mo1, g1);
    f32x8 rlo0, rhi0, rlo1, rhi1;
    #pragma unroll
    for (int jj = 0; jj < 8; jj++){
        float4 wr = w1p_l[q*8 + jj];
        float v0 = fmaf(wr.x, g0, fmaf(wr.y, p0, fmaf(wr.z, m0, wr.w)));
        float v1 = fmaf(wr.x, g1, fmaf(wr.y, p1, fmaf(wr.z, m1, wr.w)));
        rlo0[jj] = v0 > 0.f ? v0 : 0.f;
        rlo1[jj] = v1 > 0.f ? v1 : 0.f;
    }
    #pragma unroll
    for (int jj = 0; jj < 8; jj++){
        float4 wr = w1p_l[32 + q*8 + jj];
        float v0 = fmaf(wr.x, g0, fmaf(wr.y, p0, fmaf(wr.z, m0, wr.w)));
        float v1 = fmaf(wr.x, g1, fmaf(wr.y, p1, fmaf(wr.z, m1, wr.w)));
        rhi0[jj] = v0 > 0.f ? v0 : 0.f;
        rhi1[jj] = v1 > 0.f ? v1 : 0.f;
    }
    bf16x8 a0_0 = __builtin_convertvector(rlo0, bf16x8);
    bf16x8 a1_0 = __builtin_convertvector(rhi0, bf16x8);
    bf16x8 a0_1 = __builtin_convertvector(rlo1, bf16x8);
    bf16x8 a1_1 = __builtin_convertvector(rhi1, bf16x8);

    float red0[4] = {0.f, 0.f, 0.f, 0.f};
    float red1[4] = {0.f, 0.f, 0.f, 0.f};
    const floatx4 zq = {0.f, 0.f, 0.f, 0.f};

#define GATE(cb, Gofs, d0, d1)                                                \
{                                                                             \
    bf16x8 t0 = *(const bf16x8*)((cb) + (Gofs));                              \
    bf16x8 t1 = *(const bf16x8*)((cb) + (Gofs) + 512);                        \
    bf16x8 t2 = *(const bf16x8*)((cb) + (Gofs) + 1024);                       \
    bf16x8 t3 = *(const bf16x8*)((cb) + (Gofs) + 1536);                       \
    d0 = __builtin_amdgcn_mfma_f32_16x16x32_bf16(a0_0, t0, zq, 0,0,0);        \
    d1 = __builtin_amdgcn_mfma_f32_16x16x32_bf16(a0_1, t0, zq, 0,0,0);        \
    d0 = __builtin_amdgcn_mfma_f32_16x16x32_bf16(a1_0, t1, d0, 0,0,0);        \
    d1 = __builtin_amdgcn_mfma_f32_16x16x32_bf16(a1_1, t1, d1, 0,0,0);        \
    d0 = __builtin_amdgcn_mfma_f32_16x16x32_bf16(a2_0, t2, d0, 0,0,0);        \
    d1 = __builtin_amdgcn_mfma_f32_16x16x32_bf16(a2_1, t2, d1, 0,0,0);        \
    d0 = __builtin_amdgcn_mfma_f32_16x16x32_bf16(a3_0, t3, d0, 0,0,0);        \
    d1 = __builtin_amdgcn_mfma_f32_16x16x32_bf16(a3_1, t3, d1, 0,0,0);        \
}

#define EPILOG(XI, XF, XG, XO, CV, BI, BF, BG, BO, WO, RED)                   \
    _Pragma("unroll")                                                         \
    for (int r = 0; r < 4; ++r){                                              \
        float ei = __builtin_amdgcn_exp2f(fmaf(-1.442695041f, XI[r], BI));    \
        float iv = __builtin_amdgcn_rcpf(1.0f + ei);                          \
        float ef = __builtin_amdgcn_exp2f(fmaf(-1.442695041f, XF[r], BF));    \
        float fv = __builtin_amdgcn_rcpf(1.0f + ef);                          \
        float eo = __builtin_amdgcn_exp2f(fmaf(-1.442695041f, XO[r], BO));    \
        float ov = __builtin_amdgcn_rcpf(1.0f + eo);                          \
        float eg = __builtin_amdgcn_exp2f(fmaf( 2.885390082f, XG[r], BG));    \
        float gv = fmaf(-2.0f, __builtin_amdgcn_rcpf(1.0f + eg), 1.0f);       \
        float c1 = fmaf(fv, CV[r], iv*gv);                                    \
        float ec = __builtin_amdgcn_exp2f(2.885390082f * c1);                 \
        float tv = fmaf(-2.0f, __builtin_amdgcn_rcpf(1.0f + ec), 1.0f);       \
        RED[r] = fmaf(ov * tv, WO, RED[r]);                                   \
    }

#define PHASE(JH, VMCNT_STR, DO_PREFETCH)                                     \
{                                                                             \
    const int jh16 = (JH) << 4;                                               \
    const float bsi = bias_l[jh16 + l15];                                     \
    const float bsf = bias_l[jh16 + l15 + 64];                                \
    const float bsg = bias_l[jh16 + l15 + 128];                               \
    const float bso = bias_l[jh16 + l15 + 192];                               \
    const float wo  = wout_l[jh16 + l15];                                     \
    const unsigned short* cbp = wc_l + (JH)*2048 + lane*8;                    \
    floatx4 xi0,xi1,xf0,xf1,xg0,xg1,xo0,xo1;                                  \
    GATE(cbp, 0,     xi0, xi1)                                                \
    GATE(cbp, 8192,  xf0, xf1)                                                \
    GATE(cbp, 16384, xg0, xg1)                                                \
    GATE(cbp, 24576, xo0, xo1)                                                \
    asm volatile("s_waitcnt vmcnt(" VMCNT_STR ")" ::: "memory");              \
    const float* cbf0 = (const float*)(Rb + ((JH)&1)*2048);                   \
    const float* cbf1 = (const float*)(Rb + ((JH)&1)*2048 + 1024);            \
    float c00[4], c01[4];                                                     \
    _Pragma("unroll")                                                         \
    for (int r = 0; r < 4; ++r){                                              \
        c00[r] = cbf0[(q*4+r)*16 + l15];                                      \
        c01[r] = cbf1[(q*4+r)*16 + l15];                                      \
    }                                                                         \
    EPILOG(xi0, xf0, xg0, xo0, c00, bsi, bsf, bsg, bso, wo, red0)             \
    EPILOG(xi1, xf1, xg1, xo1, c01, bsi, bsf, bsg, bso, wo, red1)             \
    if (DO_PREFETCH){                                                         \
        asm volatile("s_waitcnt lgkmcnt(0)" ::: "memory");                    \
        GLD_LDS16(c0s0 + ((JH)+2)*16, Rb + ((JH)&1)*2048);                    \
        GLD_LDS16(c0s1 + ((JH)+2)*16, Rb + ((JH)&1)*2048 + 1024);             \
    }                                                                         \
}

    PHASE(0, "2", 1)
    PHASE(1, "2", 1)
    PHASE(2, "2", 0)
    PHASE(3, "0", 0)

#undef PHASE
#undef EPILOG
#undef GATE

    // ---- reduce over l15 (16-lane butterfly), store both sets ----
    #pragma unroll
    for (int mset = 1; mset < 16; mset <<= 1)
        #pragma unroll
        for (int r = 0; r < 4; r++){
            red0[r] += __shfl_xor(red0[r], mset, 64);
            red1[r] += __shfl_xor(red1[r], mset, 64);
        }

    if (l15 == 0){
        long orow = row0 + q*4;
        #pragma unroll
        for (int r = 0; r < 4; r++){
            out[orow + r]      = red0[r] + bout0;
            out[orow + 16 + r] = red1[r] + bout0;
        }
    }
}

extern "C" void kernel_launch(void* const* d_in, const int* in_sizes, int n_in,
                              void* d_out, int out_size, void* d_ws, size_t ws_size,
                              hipStream_t stream)
{
    const float* grad  = (const float*)d_in[0];
    const float* param = (const float*)d_in[1];
    const float* mom   = (const float*)d_in[2];
    const float* h0    = (const float*)d_in[3];
    const float* c0    = (const float*)d_in[4];
    const float* W1    = (const float*)d_in[5];
    const float* b1    = (const float*)d_in[6];
    const float* W2    = (const float*)d_in[7];
    const float* b2    = (const float*)d_in[8];
    const float* W_ih  = (const float*)d_in[9];
    const float* W_hh  = (const float*)d_in[10];
    const float* b_ih  = (const float*)d_in[11];
    const float* b_hh  = (const float*)d_in[12];
    const float* Wout  = (const float*)d_in[13];
    const float* bout  = (const float*)d_in[14];

    unsigned short* wc = (unsigned short*)d_ws;
    float* biasc       = (float*)((char*)d_ws + 65536);

    prep_kernel<<<16, 256, 0, stream>>>(W2, b2, W_ih, W_hh, b_ih, b_hh, wc, biasc);

    const int nblocks = 524288 / 512;   // 1024
    main_kernel<<<nblocks, 1024, 0, stream>>>(grad, param, mom, h0, c0,
                                              W1, b1, Wout, bout, wc, biasc,
                                              (float*)d_out);
}

// Round 5
// 310.956 us; speedup vs baseline: 1.3056x; 1.3056x over previous
//
#include <hip/hip_runtime.h>
#include <hip/hip_bf16.h>
#include <stdint.h>

// B=524288, H=64, D=1. fp32 in/out.
// R7 = R0 (104us proven baseline: 512-thr blocks, 16 rows/wave, 128 rows/
// block, 4096 blocks) + only the three proven/clear deltas:
//  1. HW cvt_pk bf16 packing (R5-proven: VALU busy 52->41us)
//  2. zero-C MFMA init + biases prescaled (-log2e / +2log2e) folded into
//     the epilogue exp2 fmas (R5-proven correct)
//  3. c0 loads hoisted pre-MFMA with depth-2 group pipeline (R0 loaded them
//     AFTER all MFMAs -> ~0 cover; now 400-700+ cyc cover, <=12 regs live).
//     MFMA jh-grouped (4 live acc quads) so each group's epilogue retires
//     its c0 regs.
// Lesson R4/R6b: 1024-thr blocks => hipcc caps at 64 VGPR and spills
// (WRITE_SIZE 51/305 MB). Stay at 512 threads.

typedef __attribute__((ext_vector_type(8))) __bf16  bf16x8;
typedef __attribute__((ext_vector_type(8))) float   f32x8;
typedef __attribute__((ext_vector_type(4))) float   floatx4;

__device__ __forceinline__ unsigned short f2bf_bits(float x){
    unsigned u = __builtin_bit_cast(unsigned, x);
    u = u + 0x7fffu + ((u >> 16) & 1u);          // RNE
    return (unsigned short)(u >> 16);
}
__device__ __forceinline__ bf16x8 pack8(float4 a, float4 b){
    f32x8 t;
    t[0]=a.x; t[1]=a.y; t[2]=a.z; t[3]=a.w;
    t[4]=b.x; t[5]=b.y; t[6]=b.z; t[7]=b.w;
    return __builtin_convertvector(t, bf16x8);   // v_cvt_pk_bf16_f32, RNE
}

// ---------------------------------------------------------------------------
// Prep (unchanged, proven correct): Wc[256x128] bf16 in MFMA-B fragment
// order; biasc[n] = b_ih+b_hh+W_ih@b2 (raw; prescaling happens at staging).
// ---------------------------------------------------------------------------
__global__ __launch_bounds__(256) void prep_kernel(
    const float* __restrict__ W2, const float* __restrict__ b2,
    const float* __restrict__ W_ih, const float* __restrict__ W_hh,
    const float* __restrict__ b_ih, const float* __restrict__ b_hh,
    unsigned short* __restrict__ wc, float* __restrict__ biasc)
{
    __shared__ float W2s[64*64];
    __shared__ float b2s[64];
    __shared__ float wihs[16*64];
    const int tid = threadIdx.x;
    const int b   = blockIdx.x;          // 0..15

    for (int i = 0; i < 4; i++){
        int idx = i*1024 + tid*4;
        *(float4*)(W2s + idx) = *(const float4*)(W2 + idx);
    }
    if (tid < 64) b2s[tid] = b2[tid];
    {
        int idx = tid*4;
        *(float4*)(wihs + idx) = *(const float4*)(W_ih + b*16*64 + idx);
    }
    __syncthreads();

    const int nl = tid >> 4;
    const int n  = b*16 + nl;
    const int jg = tid & 15;
    const int j  = jg*4;
    const int T  = n >> 4;

    float a0=0.f, a1=0.f, a2=0.f, a3=0.f;
    for (int h = 0; h < 64; h++){
        float wv = wihs[nl*64 + h];
        const float* w2r = W2s + h*64 + j;
        a0 += wv*w2r[0]; a1 += wv*w2r[1]; a2 += wv*w2r[2]; a3 += wv*w2r[3];
    }
    auto store4 = [&](int k, float v0, float v1, float v2, float v3){
        int s    = k >> 5;
        int lane = ((k >> 3) & 3)*16 + (n & 15);
        int off  = (T*4 + s)*512 + lane*8 + (k & 7);
        ushort4 v; v.x=f2bf_bits(v0); v.y=f2bf_bits(v1); v.z=f2bf_bits(v2); v.w=f2bf_bits(v3);
        *(ushort4*)(wc + off) = v;
    };
    store4(j, a0, a1, a2, a3);
    {
        const float* src = W_hh + n*64 + j;
        store4(64 + j, src[0], src[1], src[2], src[3]);
    }
    if (jg == 0){
        float s = b_ih[n] + b_hh[n];
        for (int h = 0; h < 64; h++) s += wihs[nl*64 + h]*b2s[h];
        biasc[n] = s;
    }
}

// ---------------------------------------------------------------------------
// Main: 512 threads = 8 waves, 128 rows/block, 4096 blocks.
// Wave w: rows [row0+16w, row0+16w+16), all 256 gate cols, jh-grouped.
// ---------------------------------------------------------------------------
__global__ __launch_bounds__(512, 4) void main_kernel(
    const float* __restrict__ grad, const float* __restrict__ param,
    const float* __restrict__ mom,  const float* __restrict__ h0,
    const float* __restrict__ c0,   const float* __restrict__ W1,
    const float* __restrict__ b1,   const float* __restrict__ Wout,
    const float* __restrict__ bout,
    const unsigned short* __restrict__ wc, const float* __restrict__ biasc,
    float* __restrict__ out)
{
    __shared__ __align__(16) unsigned short wc_l[32768];  // 64 KB
    __shared__ float  bias_l[256];   // prescaled: -log2e*b (i,f,o), +2log2e*b (g)
    __shared__ float4 w1p_l[64];     // {W1[j][0..2], b1[j]}
    __shared__ float  wout_l[64];

    const int tid  = threadIdx.x;
    const int lane = tid & 63;
    const int w    = tid >> 6;       // 0..7
    const int l15  = lane & 15;
    const int q    = lane >> 4;
    const long row0 = (long)blockIdx.x * 128;

    // ---- stage Wc + tables into LDS (single barrier) ----
    {
        const float4* src = (const float4*)wc;
        float4*       dst = (float4*)wc_l;
        #pragma unroll
        for (int i = 0; i < 8; i++)
            dst[i*512 + tid] = src[i*512 + tid];
    }
    if (tid < 256){
        float sc = ((tid >> 6) == 2) ? 2.885390082f : -1.442695041f;
        bias_l[tid] = sc * biasc[tid];
    } else if (tid < 320){
        int j = tid - 256;
        w1p_l[j] = make_float4(W1[j*3], W1[j*3+1], W1[j*3+2], b1[j]);
    } else if (tid < 384){
        wout_l[tid - 320] = Wout[tid - 320];
    }

    // ---- per-lane A-row input loads (issued under staging) ----
    const long rA = row0 + w*16 + l15;          // this lane's A row
    float g = grad[rA], p = param[rA], mo = mom[rA];
    const float* hrow = h0 + rA*64;
    float4 ha = *(const float4*)(hrow + q*8);
    float4 hb = *(const float4*)(hrow + q*8 + 4);
    float4 hc = *(const float4*)(hrow + 32 + q*8);
    float4 hd = *(const float4*)(hrow + 32 + q*8 + 4);
    const float bout0 = bout[0];

    __syncthreads();   // wc_l / bias_l / w1p_l / wout_l ready

    // ---- A-fragment build (r part from the tiny MLP, h0 part packed) ----
    float m = fmaf(0.9f, mo, g);
    f32x8 rlo, rhi;
    #pragma unroll
    for (int jj = 0; jj < 8; jj++){
        float4 wr = w1p_l[q*8 + jj];
        float v = fmaf(wr.x, g, fmaf(wr.y, p, fmaf(wr.z, m, wr.w)));
        rlo[jj] = v > 0.f ? v : 0.f;
    }
    #pragma unroll
    for (int jj = 0; jj < 8; jj++){
        float4 wr = w1p_l[32 + q*8 + jj];
        float v = fmaf(wr.x, g, fmaf(wr.y, p, fmaf(wr.z, m, wr.w)));
        rhi[jj] = v > 0.f ? v : 0.f;
    }
    bf16x8 afr0 = __builtin_convertvector(rlo, bf16x8);
    bf16x8 afr1 = __builtin_convertvector(rhi, bf16x8);
    bf16x8 afr2 = pack8(ha, hb);
    bf16x8 afr3 = pack8(hc, hd);

    // ---- c0 depth-2 pipeline: groups 0,1 issued here (cover: whole group-0
    // MFMA block ~400+ cyc; group1 ~700+); jh+2 issued at top of group jh ----
    const float* c0b = c0 + (rA & ~15L)*64 + (q*4)*64 + l15;  // rows w*16+q*4.., col l15
    float c0v0[4], c0v1[4], c0v2[4], c0v3[4];
    #pragma unroll
    for (int r = 0; r < 4; ++r) c0v0[r] = c0b[r*64];
    #pragma unroll
    for (int r = 0; r < 4; ++r) c0v1[r] = c0b[r*64 + 16];

    float red[4] = {0.f, 0.f, 0.f, 0.f};
    const floatx4 zq = {0.f, 0.f, 0.f, 0.f};

#define GATE1(cb, Gofs, d)                                                    \
{                                                                             \
    bf16x8 t0 = *(const bf16x8*)((cb) + (Gofs));                              \
    bf16x8 t1 = *(const bf16x8*)((cb) + (Gofs) + 512);                        \
    bf16x8 t2 = *(const bf16x8*)((cb) + (Gofs) + 1024);                       \
    bf16x8 t3 = *(const bf16x8*)((cb) + (Gofs) + 1536);                       \
    d = __builtin_amdgcn_mfma_f32_16x16x32_bf16(afr0, t0, zq, 0,0,0);         \
    d = __builtin_amdgcn_mfma_f32_16x16x32_bf16(afr1, t1, d,  0,0,0);         \
    d = __builtin_amdgcn_mfma_f32_16x16x32_bf16(afr2, t2, d,  0,0,0);         \
    d = __builtin_amdgcn_mfma_f32_16x16x32_bf16(afr3, t3, d,  0,0,0);         \
}

#define EPILOG(XI, XF, XG, XO, CV, BI, BF, BG, BO, WO)                        \
    _Pragma("unroll")                                                         \
    for (int r = 0; r < 4; ++r){                                              \
        float ei = __builtin_amdgcn_exp2f(fmaf(-1.442695041f, XI[r], BI));    \
        float iv = __builtin_amdgcn_rcpf(1.0f + ei);                          \
        float ef = __builtin_amdgcn_exp2f(fmaf(-1.442695041f, XF[r], BF));    \
        float fv = __builtin_amdgcn_rcpf(1.0f + ef);                          \
        float eo = __builtin_amdgcn_exp2f(fmaf(-1.442695041f, XO[r], BO));    \
        float ov = __builtin_amdgcn_rcpf(1.0f + eo);                          \
        float eg = __builtin_amdgcn_exp2f(fmaf( 2.885390082f, XG[r], BG));    \
        float gv = fmaf(-2.0f, __builtin_amdgcn_rcpf(1.0f + eg), 1.0f);       \
        float c1 = fmaf(fv, CV[r], iv*gv);                                    \
        float ec = __builtin_amdgcn_exp2f(2.885390082f * c1);                 \
        float tv = fmaf(-2.0f, __builtin_amdgcn_rcpf(1.0f + ec), 1.0f);       \
        red[r] = fmaf(ov * tv, WO, red[r]);                                   \
    }

#define PHASE(JH, CV, PRE_CV, DO_PRE)                                         \
{                                                                             \
    if (DO_PRE){                                                              \
        _Pragma("unroll")                                                     \
        for (int r = 0; r < 4; ++r) PRE_CV[r] = c0b[r*64 + ((JH)+2)*16];      \
    }                                                                         \
    const int jh16 = (JH) << 4;                                               \
    const float bsi = bias_l[jh16 + l15];                                     \
    const float bsf = bias_l[jh16 + l15 + 64];                                \
    const float bsg = bias_l[jh16 + l15 + 128];                               \
    const float bso = bias_l[jh16 + l15 + 192];                               \
    const float wo  = wout_l[jh16 + l15];                                     \
    const unsigned short* cbp = wc_l + (JH)*2048 + lane*8;                    \
    floatx4 xi, xf, xg, xo;                                                   \
    GATE1(cbp, 0,     xi)                                                     \
    GATE1(cbp, 8192,  xf)                                                     \
    GATE1(cbp, 16384, xg)                                                     \
    GATE1(cbp, 24576, xo)                                                     \
    EPILOG(xi, xf, xg, xo, CV, bsi, bsf, bsg, bso, wo)                        \
}

    PHASE(0, c0v0, c0v2, 1)
    PHASE(1, c0v1, c0v3, 1)
    PHASE(2, c0v2, c0v0, 0)
    PHASE(3, c0v3, c0v0, 0)

#undef PHASE
#undef EPILOG
#undef GATE1

    // ---- reduce over l15 (16-lane butterfly), store ----
    #pragma unroll
    for (int mset = 1; mset < 16; mset <<= 1)
        #pragma unroll
        for (int r = 0; r < 4; r++)
            red[r] += __shfl_xor(red[r], mset, 64);

    if (l15 == 0){
        long orow = row0 + w*16 + q*4;
        #pragma unroll
        for (int r = 0; r < 4; r++)
            out[orow + r] = red[r] + bout0;
    }
}

extern "C" void kernel_launch(void* const* d_in, const int* in_sizes, int n_in,
                              void* d_out, int out_size, void* d_ws, size_t ws_size,
                              hipStream_t stream)
{
    const float* grad  = (const float*)d_in[0];
    const float* param = (const float*)d_in[1];
    const float* mom   = (const float*)d_in[2];
    const float* h0    = (const float*)d_in[3];
    const float* c0    = (const float*)d_in[4];
    const float* W1    = (const float*)d_in[5];
    const float* b1    = (const float*)d_in[6];
    const float* W2    = (const float*)d_in[7];
    const float* b2    = (const float*)d_in[8];
    const float* W_ih  = (const float*)d_in[9];
    const float* W_hh  = (const float*)d_in[10];
    const float* b_ih  = (const float*)d_in[11];
    const float* b_hh  = (const float*)d_in[12];
    const float* Wout  = (const float*)d_in[13];
    const float* bout  = (const float*)d_in[14];

    unsigned short* wc = (unsigned short*)d_ws;
    float* biasc       = (float*)((char*)d_ws + 65536);

    prep_kernel<<<16, 256, 0, stream>>>(W2, b2, W_ih, W_hh, b_ih, b_hh, wc, biasc);

    const int nblocks = 524288 / 128;   // 4096
    main_kernel<<<nblocks, 512, 0, stream>>>(grad, param, mom, h0, c0,
                                             W1, b1, Wout, bout, wc, biasc,
                                             (float*)d_out);
}